// Round 8
// baseline (8128.468 us; speedup 1.0000x reference)
//
#include <hip/hip_runtime.h>
#include <hip/hip_bf16.h>

// Problem constants (B=256, T=512, H=512, IN=1, future=64)
#define TT  512
#define BB  256
#define HH  512
#define FUT 64
#define NBLK 256           // 8 batch-groups x 32 unit-blocks, XCD-local

// Output dtype FP32. Beacons: float 2^(20+code)*(1+m/128):
//  0: n_in!=22  1: in_sizes mismatch @m  2: ws too small  6: out_size wrong
// r20 = r19 structure + two hard fixes:
//  (1) race-free rendezvous: xt entries are write-once; every block polls
//      until ALL 256 are nonzero, THEN computes the (identical) assignment.
//      r19 trusted a relaxed arrive counter -> stale table reads -> blocks
//      disagreed on placement -> nondeterministic wrong results + stalls.
//  (2) h/opb STORES always sc0 sc1 (IC write-through, r14-proven). Only the
//      broadcast LOADS switch mode, gated by a runtime coherence probe per
//      homogeneous group: pre-read line -> producer stores gen1 (drained)
//      -> consumer must see it FIRST-READ after flag -> repeat gen2
//      (models ring-slot rewrite of a cached line). All 31 pass twice ->
//      sc0 loads (XCD L2-served dedup); else sc0sc1 fallback (correct,
//      16MB/step vs r18's 24). Flags always poll via IC.
// Fused per block: phase t = L0(t)+L1(t-1) off one h0(t-1) read; 16 units;
// Wih1+Whh1 in LDS (128KB); Whh0 streamed cached (own 64KB slice, L2).
// Spin caps everywhere: protocol failure -> passed:false, not a hang.

struct Hdr { int dtflag; };

typedef __attribute__((ext_vector_type(8))) short short8;
typedef __attribute__((ext_vector_type(4))) float floatx4;

#define OFF_XT   4096                       // xtab[256] (write-once)
#define OFF_FLG  8192                       // flags: 8 bg x 32 ints
#define OFF_OP   12288                      // oparts: 8 bg x 2 x 32 x 32 f32
#define OFF_PRB  98304                      // probe: 8 bg x 64 ints
#define OFF_H0   131072                     // 8 bg x 2 slot x 32x512 bf16
#define OFF_H1   (OFF_H0 + 524288)
#define OFF_W    (OFF_H1 + 524288)
#define WSZ      ((size_t)2048*512*2)       // 2MB bf16 matrix
#define NEED_WS  (OFF_W + 6*WSZ)            // ~13.8MB

#define SPIN_CAP  (1L << 18)
#define RDV_CAP   (1L << 20)
#define PROBE_CAP (1L << 15)
#define MAG1 0x11C0FFEE
#define MAG2 0x22C0FFEE

__device__ __forceinline__ float bf2f(short s) {
  unsigned u = ((unsigned)(unsigned short)s) << 16;
  return __builtin_bit_cast(float, u);
}
__device__ __forceinline__ short f2bf(float f) {
  unsigned u = __builtin_bit_cast(unsigned, f);
  u = u + 0x7FFFu + ((u >> 16) & 1u);
  return (short)(u >> 16);
}
__device__ __forceinline__ float ldf(const void* p, long i, int dt) {
  return dt ? ((const float*)p)[i] : bf2f(((const short*)p)[i]);
}

// ---- system-scope (IC) scalar helpers ----
__device__ __forceinline__ int ld4s(const int* p) {
  return __hip_atomic_load(p, __ATOMIC_RELAXED, __HIP_MEMORY_SCOPE_SYSTEM);
}
__device__ __forceinline__ void st4s(int* p, int v) {
  __hip_atomic_store(p, v, __ATOMIC_RELAXED, __HIP_MEMORY_SCOPE_SYSTEM);
}
__device__ __forceinline__ void fadds(int* p) {
  __hip_atomic_fetch_add(p, 1, __ATOMIC_RELAXED, __HIP_MEMORY_SCOPE_SYSTEM);
}
// local-mode 4B load (sc0: bypass L1, serve from XCD L2), self-waiting
__device__ __forceinline__ int ld4l(const int* p) {
  int v;
  asm volatile("global_load_dword %0, %1, off sc0\n\ts_waitcnt vmcnt(0)"
               : "=v"(v) : "v"(p));
  return v;
}
__device__ __forceinline__ void pollge(const int* p, int tgt, long cap) {
  long g = 0;
  while (ld4s(p) < tgt) {
    __builtin_amdgcn_s_sleep(2);
    if (++g > cap) break;
  }
}

// ---- 16B h ops. Loads templated on coherence mode; stores ALWAYS sc0sc1.
// Loads are NOT ready until a manual s_waitcnt vmcnt(N) (WAITV).
template<int IC>
__device__ __forceinline__ short8 LDH(const short* p) {
  short8 v;
  if constexpr (IC)
    asm volatile("global_load_dwordx4 %0, %1, off sc0 sc1" : "=v"(v) : "v"(p));
  else
    asm volatile("global_load_dwordx4 %0, %1, off sc0" : "=v"(v) : "v"(p));
  return v;
}
__device__ __forceinline__ short8 LDW(const short* p) {  // cached (weights)
  short8 v;
  asm volatile("global_load_dwordx4 %0, %1, off" : "=v"(v) : "v"(p));
  return v;
}
__device__ __forceinline__ void STH(short* p, short8 v) {
  asm volatile("global_store_dwordx4 %0, %1, off sc0 sc1"
               :: "v"(p), "v"(v) : "memory");
}
#define WAITV(N) do { asm volatile("s_waitcnt vmcnt(" #N ")" ::: "memory"); \
                      __builtin_amdgcn_sched_barrier(0); } while (0)

__global__ void beacon_kernel(float* dout, float v) {
  if (threadIdx.x == 0) dout[0] = v;
}

__global__ __launch_bounds__(256) void probe1_kernel(const void* w, Hdr* hdr) {
  const int tid = threadIdx.x;
  const short* s = (const short*)w;
  float mx = 0.f;
  #pragma unroll
  for (int i = 0; i < 16; ++i) {
    float v = fabsf(bf2f(s[tid * 16 + i]));
    if (!(v == v)) v = 1e30f;
    mx = fmaxf(mx, v);
  }
  #pragma unroll
  for (int off = 32; off > 0; off >>= 1) mx = fmaxf(mx, __shfl_down(mx, off));
  __shared__ float wmax[4];
  if ((tid & 63) == 0) wmax[tid >> 6] = mx;
  __syncthreads();
  if (tid == 0) {
    float m = fmaxf(fmaxf(wmax[0], wmax[1]), fmaxf(wmax[2], wmax[3]));
    hdr->dtflag = (m > 1000.f) ? 1 : 0;
  }
}

__global__ __launch_bounds__(256) void cvt_kernel(const void* src, short* dst,
                                                  const Hdr* hdr) {
  const int dt = hdr->dtflag;
  const long i = ((long)blockIdx.x * 256 + threadIdx.x);
  if (dt) {
    const float4 v = ((const float4*)src)[i];
    short4 o;
    o.x = f2bf(v.x); o.y = f2bf(v.y); o.z = f2bf(v.z); o.w = f2bf(v.w);
    ((short4*)dst)[i] = o;
  } else {
    ((short4*)dst)[i] = ((const short4*)src)[i];
  }
}

// ---------------- phase machinery macros (used inside lstm_run) ----------
#define H0S(STEP) (h0ring + (size_t)(((STEP) & 1)) * 16384)
#define H1S(STEP) (h1ring + (size_t)(((STEP) & 1)) * 16384)
#define WLD(S, KB) \
  (*(const short8*)(WlP + (((S)*64 + ((KB)*4 + q))*64 + (mt*16 + ln))*8))

#define STAGE16(SLOT, WG)                                                    \
  for (int i = tid; i < 4096; i += 512) {                                    \
    const int ks_ = i & 63, r_ = i >> 6;                                     \
    const long gr = (long)((r_ & 3)*512 + U0 + (r_ >> 2))*512 + ks_*8;       \
    *(short8*)(WlP + (((SLOT)*64 + ks_)*64 + r_)*8) =                        \
        *(const short8*)((WG) + gr);                                         \
  }

#define BIASLD(BA, B1, B2)                                                   \
  if (tid < 64) {                                                            \
    const long j_ = (long)(tid & 3)*512 + U0 + (tid >> 2);                   \
    (BA)[tid] = ldf((B1), j_, dt) + ldf((B2), j_, dt);                       \
  }
#define WIHLD(WP)                                                            \
  if (tid < 64) {                                                            \
    const long j_ = (long)(tid & 3)*512 + U0 + (tid >> 2);                   \
    wihL[tid] = ldf((WP), j_, dt);                                           \
  }

// all waves' lanes<32 poll the 32 per-producer flag words via IC
#define POLLF(TGT)                                                           \
  { long gg_ = 0;                                                            \
    for (;;) {                                                               \
      int v_ = 0x7fffffff;                                                   \
      if (lane < 32) v_ = ld4s(myflags + lane);                              \
      if (__all(v_ >= (TGT))) break;                                         \
      __builtin_amdgcn_s_sleep(2);                                           \
      if (++gg_ > SPIN_CAP) break;                                           \
    } }

#define ZV ((floatx4){0.f, 0.f, 0.f, 0.f})

// fused: a0 += Wstream.h0 ; a1 += Wl0.h0 + Wl1.h1   (12 loads/group x4)
#define GSEG_F(H0P, H1P, WSP)                                                \
  { const short* hp0_ = (H0P) + hoff;                                        \
    const short* hp1_ = (H1P) + hoff;                                        \
    const short* wp_  = (WSP) + wrowoff;                                     \
    short8 bw[2][4], c0b[2][4], c1b[2][4];                                   \
    _Pragma("unroll")                                                        \
    for (int i = 0; i < 4; ++i) {                                            \
      bw[0][i]  = LDW(wp_ + i*32);                                           \
      c0b[0][i] = LDH<IC>(hp0_ + i*32);                                      \
      c1b[0][i] = LDH<IC>(hp1_ + i*32);                                      \
    }                                                                        \
    _Pragma("unroll")                                                        \
    for (int g = 0; g < 4; ++g) {                                            \
      if (g < 3) {                                                           \
        _Pragma("unroll")                                                    \
        for (int i = 0; i < 4; ++i) {                                        \
          const int kb_ = (g+1)*4 + i;                                       \
          bw[(g+1)&1][i]  = LDW(wp_ + kb_*32);                               \
          c0b[(g+1)&1][i] = LDH<IC>(hp0_ + kb_*32);                          \
          c1b[(g+1)&1][i] = LDH<IC>(hp1_ + kb_*32);                          \
        }                                                                    \
        WAITV(12);                                                           \
      } else { WAITV(0); }                                                   \
      _Pragma("unroll")                                                      \
      for (int i = 0; i < 4; ++i) {                                          \
        const int kb_ = g*4 + i;                                             \
        a0 = __builtin_amdgcn_mfma_f32_16x16x32_bf16(                        \
            bw[g&1][i], c0b[g&1][i], a0, 0, 0, 0);                           \
        a1 = __builtin_amdgcn_mfma_f32_16x16x32_bf16(                        \
            WLD(0, kb_), c0b[g&1][i], a1, 0, 0, 0);                          \
        a1 = __builtin_amdgcn_mfma_f32_16x16x32_bf16(                        \
            WLD(1, kb_), c1b[g&1][i], a1, 0, 0, 0);                          \
      }                                                                      \
    } }

// L0 only: a0 += Wstream.h0   (8 loads/group x4)
#define GSEG_A(H0P, WSP)                                                     \
  { const short* hp0_ = (H0P) + hoff;                                        \
    const short* wp_  = (WSP) + wrowoff;                                     \
    short8 bw[2][4], c0b[2][4];                                              \
    _Pragma("unroll")                                                        \
    for (int i = 0; i < 4; ++i) {                                            \
      bw[0][i]  = LDW(wp_ + i*32);                                           \
      c0b[0][i] = LDH<IC>(hp0_ + i*32);                                      \
    }                                                                        \
    _Pragma("unroll")                                                        \
    for (int g = 0; g < 4; ++g) {                                            \
      if (g < 3) {                                                           \
        _Pragma("unroll")                                                    \
        for (int i = 0; i < 4; ++i) {                                        \
          const int kb_ = (g+1)*4 + i;                                       \
          bw[(g+1)&1][i]  = LDW(wp_ + kb_*32);                               \
          c0b[(g+1)&1][i] = LDH<IC>(hp0_ + kb_*32);                          \
        }                                                                    \
        WAITV(8);                                                            \
      } else { WAITV(0); }                                                   \
      _Pragma("unroll")                                                      \
      for (int i = 0; i < 4; ++i)                                            \
        a0 = __builtin_amdgcn_mfma_f32_16x16x32_bf16(                        \
            bw[g&1][i], c0b[g&1][i], a0, 0, 0, 0);                           \
    } }

// L1 only: a1 += Wl0.h0 + Wl1.h1   (8 loads/group x4)
#define GSEG_B(H0P, H1P)                                                     \
  { const short* hp0_ = (H0P) + hoff;                                        \
    const short* hp1_ = (H1P) + hoff;                                        \
    short8 c0b[2][4], c1b[2][4];                                             \
    _Pragma("unroll")                                                        \
    for (int i = 0; i < 4; ++i) {                                            \
      c0b[0][i] = LDH<IC>(hp0_ + i*32);                                      \
      c1b[0][i] = LDH<IC>(hp1_ + i*32);                                      \
    }                                                                        \
    _Pragma("unroll")                                                        \
    for (int g = 0; g < 4; ++g) {                                            \
      if (g < 3) {                                                           \
        _Pragma("unroll")                                                    \
        for (int i = 0; i < 4; ++i) {                                        \
          const int kb_ = (g+1)*4 + i;                                       \
          c0b[(g+1)&1][i] = LDH<IC>(hp0_ + kb_*32);                          \
          c1b[(g+1)&1][i] = LDH<IC>(hp1_ + kb_*32);                          \
        }                                                                    \
        WAITV(8);                                                            \
      } else { WAITV(0); }                                                   \
      _Pragma("unroll")                                                      \
      for (int i = 0; i < 4; ++i) {                                          \
        const int kb_ = g*4 + i;                                             \
        a1 = __builtin_amdgcn_mfma_f32_16x16x32_bf16(                        \
            WLD(0, kb_), c0b[g&1][i], a1, 0, 0, 0);                          \
        a1 = __builtin_amdgcn_mfma_f32_16x16x32_bf16(                        \
            WLD(1, kb_), c1b[g&1][i], a1, 0, 0, 0);                          \
      }                                                                      \
    } }

// epilogue. lane holds all 4 gates of (unit u, batch b) per layer.
// MODE 0: sv=x[b][TV]; 1: none; 2: sv=obuf[b]. Ends drained+synced.
#define EPIX(D0, D1, MODE, HEAD, PAR, H0ST, H1ST, TVAL)                      \
  { float sv_ = 0.f;                                                         \
    if ((MODE) == 0)      sv_ = ldf(x, (long)(B0 + b)*TT + (TVAL), dt);      \
    else if ((MODE) == 2) sv_ = obuf[b];                                     \
    if (D0) {                                                                \
      float gi = a0[0] + bsA[u*4+0] + sv_*wihL[u*4+0];                       \
      float gf = a0[1] + bsA[u*4+1] + sv_*wihL[u*4+1];                       \
      float gg = a0[2] + bsA[u*4+2] + sv_*wihL[u*4+2];                       \
      float go = a0[3] + bsA[u*4+3] + sv_*wihL[u*4+3];                       \
      const float I = 1.f/(1.f+expf(-gi));                                   \
      const float F = 1.f/(1.f+expf(-gf));                                   \
      const float G = tanhf(gg);                                             \
      const float O = 1.f/(1.f+expf(-go));                                   \
      cst0 = F*cst0 + I*G;                                                   \
      hb0[b*16 + u] = f2bf(O * tanhf(cst0));                                 \
    }                                                                        \
    if (D1) {                                                                \
      float gi = a1[0] + bsB[u*4+0];                                         \
      float gf = a1[1] + bsB[u*4+1];                                         \
      float gg = a1[2] + bsB[u*4+2];                                         \
      float go = a1[3] + bsB[u*4+3];                                         \
      const float I = 1.f/(1.f+expf(-gi));                                   \
      const float F = 1.f/(1.f+expf(-gf));                                   \
      const float G = tanhf(gg);                                             \
      const float O = 1.f/(1.f+expf(-go));                                   \
      cst1 = F*cst1 + I*G;                                                   \
      const float hv_ = O * tanhf(cst1);                                     \
      hb1[b*16 + u] = f2bf(hv_);                                             \
      if (HEAD) {                                                            \
        float po_ = fw * hv_;                                                \
        po_ += __shfl_xor(po_, 16);                                          \
        po_ += __shfl_xor(po_, 32);                                          \
        if (lane < 16) opl[mt*32 + b] = po_;                                 \
      }                                                                      \
    }                                                                        \
    __syncthreads();                                                         \
    if ((D0) && tid < 64)                                                    \
      STH(H0S(H0ST) + (long)(tid>>1)*512 + U0 + (tid&1)*8,                   \
          *(const short8*)(hb0 + (tid>>1)*16 + (tid&1)*8));                  \
    if ((D1) && tid >= 64 && tid < 128) {                                    \
      const int t_ = tid - 64;                                               \
      STH(H1S(H1ST) + (long)(t_>>1)*512 + U0 + (t_&1)*8,                     \
          *(const short8*)(hb1 + (t_>>1)*16 + (t_&1)*8));                    \
    }                                                                        \
    if ((HEAD) && tid < 32) {                                                \
      union { float f; int i; } uo_;                                         \
      uo_.f = opl[tid] + opl[32+tid] + opl[64+tid] + opl[96+tid];            \
      st4s((int*)(opb + (PAR)*1024 + tid*32 + ug), uo_.i);                   \
    }                                                                        \
    asm volatile("s_waitcnt vmcnt(0)" ::: "memory");                         \
    __syncthreads();                                                         \
  }

#define PUBF(V) do { if (tid == 0) st4s(myflags + ug, (V)); } while (0)

// A-phase: compute o(s-1) per batch from 32 block-partials; write dout col
#define OBUFC(PAR, OBIAS, OUTCOL)                                            \
  if (tid < 32) {                                                            \
    const float* pp_ = opb + (PAR)*1024 + tid*32;                            \
    short8 r_[8];                                                            \
    _Pragma("unroll")                                                        \
    for (int j = 0; j < 8; ++j)                                              \
      r_[j] = LDH<IC>((const short*)(pp_ + j*4));                            \
    WAITV(0);                                                                \
    float s_ = 0.f;                                                          \
    _Pragma("unroll")                                                        \
    for (int j = 0; j < 8; ++j) {                                            \
      union { short8 v; float f[4]; } cv_; cv_.v = r_[j];                    \
      s_ += cv_.f[0] + cv_.f[1] + cv_.f[2] + cv_.f[3];                       \
    }                                                                        \
    const float o_ = s_ + (OBIAS);                                           \
    obuf[tid] = o_;                                                          \
    if (ug == 0) dout[(long)(B0 + tid)*FUT + (OUTCOL)] = o_;                 \
  }

template<int IC>
__device__ __forceinline__ void lstm_run(
    int dt, int bg, int ug, int tid,
    const void* x, const void* w_ih0, const void* b_ih0, const void* b_hh0,
    const void* b_ih1, const void* b_hh1, const void* fc_w, const void* fc_b,
    const void* pw_ih0, const void* pb_ih0, const void* pb_hh0,
    const void* pb_ih1, const void* pb_hh1, const void* pfc_w,
    const void* pfc_b,
    const short* Whh0c, const short* Wih1c, const short* Whh1c,
    const short* pWhh0c, const short* pWih1c, const short* pWhh1c,
    short* h0ring, short* h1ring, float* opb, int* myflags,
    float* dout,
    short* WlP, short* hb0, short* hb1,
    float* bsA, float* bsB, float* wihL, float* obuf, float* opl)
{
  const int lane = tid & 63, wv = tid >> 6;
  const int ln = lane & 15, q = lane >> 4;
  const int mt = wv >> 1, bt = wv & 1;
  const int u  = mt*4 + q;            // unit-local 0..15
  const int b  = bt*16 + ln;          // batch-local 0..31
  const int U0 = ug * 16;
  const int B0 = bg * 32;
  const long hoff = (long)b*512 + q*8;
  const int  Rr = mt*16 + ln;         // A-row within 64-row slice
  const long wrowoff = ((long)(Rr & 3)*512 + U0 + (Rr >> 2))*512 + q*8;

  float cst0 = 0.f, cst1 = 0.f;
  float fw = ldf(fc_w, U0 + u, dt);
  const float fcb  = ldf(fc_b, 0, dt);
  const float pfcb = ldf(pfc_b, 0, dt);

  // ---- warmup weights + biases ----
  STAGE16(0, Wih1c); STAGE16(1, Whh1c);
  BIASLD(bsA, b_ih0, b_hh0); BIASLD(bsB, b_ih1, b_hh1); WIHLD(w_ih0);
  __syncthreads();

  floatx4 a0, a1;
  int p = 0;
  // ---- warmup: phase t = L0(t) + L1(t-1) ----
  for (int t = 0; t < TT; ++t, ++p) {
    POLLF(p);
    a0 = ZV; a1 = ZV;
    if (t == 0) {
      GSEG_A(H0S(-1), Whh0c);
      EPIX(1, 0, 0, 0, 0, 0, 0, t);
    } else {
      GSEG_F(H0S(t-1), H1S(t-2), Whh0c);
      EPIX(1, 1, 0, 0, 0, t, t-1, t);
    }
    PUBF(p + 1);
  }
  // ---- p=512: final L1(511) + fc head partials (o(0), par 0) ----
  {
    POLLF(p);
    a1 = ZV;
    GSEG_B(H0S(511), H1S(510));
    EPIX(0, 1, 1, 1, 0, 0, 511, 0);
    PUBF(p + 1); ++p;
  }
  // ---- transition: decode weights (block-local) ----
  STAGE16(0, pWih1c); STAGE16(1, pWhh1c);
  BIASLD(bsA, pb_ih0, pb_hh0); BIASLD(bsB, pb_ih1, pb_hh1); WIHLD(pw_ih0);
  fw = ldf(pfc_w, U0 + u, dt);
  __syncthreads();
  // ---- decode: A (L0, input o) / B (L1 + head) alternating ----
  for (int s = 1; s < FUT; ++s) {
    POLLF(p);
    OBUFC((s-1) & 1, (s == 1) ? fcb : pfcb, s-1);
    a0 = ZV;
    GSEG_A(H0S(510 + s), pWhh0c);
    __syncthreads();                     // obuf ready for EPI
    EPIX(1, 0, 2, 0, 0, 511 + s, 0, 0);
    PUBF(p + 1); ++p;

    POLLF(p);
    a1 = ZV;
    GSEG_B(H0S(511 + s), H1S(510 + s));
    EPIX(0, 1, 1, 1, s & 1, 0, 511 + s, 0);
    PUBF(p + 1); ++p;
  }
  // ---- final: o(63) ----
  POLLF(p);
  if (ug == 0 && tid < 32) {
    const float* pp = opb + ((FUT-1) & 1)*1024 + tid*32;
    short8 r[8];
    #pragma unroll
    for (int j = 0; j < 8; ++j) r[j] = LDH<IC>((const short*)(pp + j*4));
    WAITV(0);
    float s = 0.f;
    #pragma unroll
    for (int j = 0; j < 8; ++j) {
      union { short8 v; float f[4]; } cv; cv.v = r[j];
      s += cv.f[0] + cv.f[1] + cv.f[2] + cv.f[3];
    }
    dout[(long)(B0 + tid)*FUT + (FUT-1)] = s + pfcb;
  }
}

__global__ __launch_bounds__(512, 1) void lstm_persist(
    const void* __restrict__ x,
    const void* __restrict__ w_ih0, const void* __restrict__ b_ih0,
    const void* __restrict__ b_hh0, const void* __restrict__ b_ih1,
    const void* __restrict__ b_hh1, const void* __restrict__ fc_w,
    const void* __restrict__ fc_b,  const void* __restrict__ pw_ih0,
    const void* __restrict__ pb_ih0, const void* __restrict__ pb_hh0,
    const void* __restrict__ pb_ih1, const void* __restrict__ pb_hh1,
    const void* __restrict__ pfc_w, const void* __restrict__ pfc_b,
    const short* __restrict__ Whh0c, const short* __restrict__ Wih1c,
    const short* __restrict__ Whh1c, const short* __restrict__ pWhh0c,
    const short* __restrict__ pWih1c, const short* __restrict__ pWhh1c,
    short* H0R, short* H1R, float* oA, int* xt, int* flg, int* prb,
    const Hdr* __restrict__ hdr, float* __restrict__ dout)
{
  __shared__ __align__(16) short Wl[2*64*64*8];   // 128KB
  __shared__ __align__(16) short hb0[512], hb1[512];
  __shared__ float bsA[64], bsB[64], wihL[64], obuf[32], opl[128];
  __shared__ int xls[256];
  __shared__ int meta[4];

  const int tid = threadIdx.x;
  const int bid = blockIdx.x;
  const int dt  = hdr->dtflag;

  // ---- race-free rendezvous: write-once entries, poll-until-complete ----
  if (tid == 0) {
    int xcc = 0;
    asm volatile("s_getreg_b32 %0, hwreg(HW_REG_XCC_ID)" : "=s"(xcc));
    __hip_atomic_store(xt + bid, (xcc & 7) + 1, __ATOMIC_RELAXED,
                       __HIP_MEMORY_SCOPE_SYSTEM);
  }
  if (tid < 64) {
    long gg = 0;
    for (;;) {
      int ok = 1;
      #pragma unroll
      for (int j = 0; j < 4; ++j) {
        int v = ld4s(xt + tid*4 + j);
        xls[tid*4 + j] = v;
        ok &= (v != 0);
      }
      if (__all(ok)) break;
      __builtin_amdgcn_s_sleep(2);
      if (++gg > RDV_CAP) break;
    }
  }
  __syncthreads();
  // ---- deterministic bijective assignment: bg k <- XCD k's first 32 ----
  if (tid == 0) {
    int total[8] = {0,0,0,0,0,0,0,0};
    for (int i = 0; i < NBLK; ++i) total[(xls[i] - 1) & 7]++;
    int cnt[8] = {0,0,0,0,0,0,0,0};
    int mybg = -1, myug = -1, nover = 0, orank = -1;
    for (int i = 0; i < NBLK; ++i) {
      const int xi = (xls[i] - 1) & 7;
      if (cnt[xi] < 32) {
        if (i == bid) { mybg = xi; myug = cnt[xi]; }
        cnt[xi]++;
      } else {
        if (i == bid) orank = nover;
        nover++;
      }
    }
    if (mybg < 0) {                       // overflow -> fill deficits
      int d = 0;
      for (int k = 0; k < 8 && mybg < 0; ++k) {
        const int miss = 32 - cnt[k];
        if (miss > 0) {
          if (orank < d + miss) { mybg = k; myug = cnt[k] + (orank - d); }
          d += miss;
        }
      }
    }
    int loc;
    if (mybg < 0 || myug < 0 || myug > 31) {  // paranoia fallback
      mybg = bid >> 5; myug = bid & 31; loc = 0;
    } else {
      loc = (total[mybg] >= 32) ? 1 : 0;      // homogeneous on one XCD?
    }
    meta[0] = mybg; meta[1] = myug; meta[2] = loc;
  }
  __syncthreads();
  const int bg = meta[0], ug = meta[1], loc = meta[2];

  // ---- runtime coherence probe (2 generations, single-shot reads) ----
  int dec = 0;
  if (tid == 0 && loc) {
    int* pb = prb + bg * 64;
    if (ug == 0) {
      pollge(pb + 4, 31, PROBE_CAP);           // all consumers pre-read
      st4s(pb, MAG1);
      asm volatile("s_waitcnt vmcnt(0)" ::: "memory");
      st4s(pb + 5, 1);                         // armed1
      pollge(pb + 6, 31, PROBE_CAP);           // gen1 done
      st4s(pb, MAG2);
      asm volatile("s_waitcnt vmcnt(0)" ::: "memory");
      st4s(pb + 7, 1);                         // armed2
      pollge(pb + 9, 31, PROBE_CAP);           // all done
      const int d = (ld4s(pb + 8) == 31) ? 2 : 1;
      st4s(pb + 10, d);
      dec = (d == 2);
    } else {
      (void)ld4l(pb);                          // pre-read: pollute caches
      fadds(pb + 4);
      pollge(pb + 5, 1, PROBE_CAP);
      int ok = (ld4l(pb) == MAG1);             // FIRST-read must see gen1
      fadds(pb + 6);
      pollge(pb + 7, 1, PROBE_CAP);
      ok = ok && (ld4l(pb) == MAG2);           // FIRST-read must see gen2
      if (ok) fadds(pb + 8);
      fadds(pb + 9);
      pollge(pb + 10, 1, PROBE_CAP);
      dec = (ld4s(pb + 10) == 2);
    }
  }
  if (tid == 0) meta[3] = dec;
  __syncthreads();
  const int uselocal = meta[3];

  short* h0ring  = H0R + (size_t)bg * 32768;      // 2 x 32x512 shorts
  short* h1ring  = H1R + (size_t)bg * 32768;
  float* opb     = oA + (size_t)bg * 2048;        // 2 par x 32 b x 32 ug
  int*   myflags = flg + bg * 32;

  if (uselocal)
    lstm_run<0>(dt, bg, ug, tid, x, w_ih0, b_ih0, b_hh0, b_ih1, b_hh1,
                fc_w, fc_b, pw_ih0, pb_ih0, pb_hh0, pb_ih1, pb_hh1,
                pfc_w, pfc_b, Whh0c, Wih1c, Whh1c, pWhh0c, pWih1c, pWhh1c,
                h0ring, h1ring, opb, myflags, dout,
                Wl, hb0, hb1, bsA, bsB, wihL, obuf, opl);
  else
    lstm_run<1>(dt, bg, ug, tid, x, w_ih0, b_ih0, b_hh0, b_ih1, b_hh1,
                fc_w, fc_b, pw_ih0, pb_ih0, pb_hh0, pb_ih1, pb_hh1,
                pfc_w, pfc_b, Whh0c, Wih1c, Whh1c, pWhh0c, pWih1c, pWhh1c,
                h0ring, h1ring, opb, myflags, dout,
                Wl, hb0, hb1, bsA, bsB, wihL, obuf, opl);
}

extern "C" void kernel_launch(void* const* d_in, const int* in_sizes, int n_in,
                              void* d_out, int out_size, void* d_ws, size_t ws_size,
                              hipStream_t stream) {
  float* dout = (float*)d_out;

  static const int exp_sizes[22] = {
    131072, 1, 2048, 1048576, 2048, 2048, 1048576, 1048576, 2048, 2048,
    512, 1, 2048, 1048576, 2048, 2048, 1048576, 1048576, 2048, 2048, 512, 1};
  int code = -1, m = 0;
  if (n_in != 22) { code = 0; m = n_in & 127; }
  else {
    for (int i = 0; i < 22; ++i)
      if (in_sizes[i] != exp_sizes[i]) { code = 1; m = i; break; }
  }
  if (code < 0 && out_size != BB * FUT) { code = 6; m = (out_size >> 8) & 127; }
  if (code < 0 && (d_ws == nullptr || ws_size < NEED_WS)) {
    code = 2; m = (int)(ws_size >> 20); if (m > 127) m = 127;
  }
  if (code >= 0) {
    float v = ldexpf(1.f + (float)m / 128.f, 20 + code);
    beacon_kernel<<<dim3(1), dim3(64), 0, stream>>>(dout, v);
    return;
  }

  const void* x      = d_in[0];
  const void* w_ih0  = d_in[2];
  const void* w_hh0  = d_in[3];
  const void* b_ih0  = d_in[4];
  const void* b_hh0  = d_in[5];
  const void* w_ih1  = d_in[6];
  const void* w_hh1  = d_in[7];
  const void* b_ih1  = d_in[8];
  const void* b_hh1  = d_in[9];
  const void* fc_w   = d_in[10];
  const void* fc_b   = d_in[11];
  const void* pw_ih0 = d_in[12];
  const void* pw_hh0 = d_in[13];
  const void* pb_ih0 = d_in[14];
  const void* pb_hh0 = d_in[15];
  const void* pw_ih1 = d_in[16];
  const void* pw_hh1 = d_in[17];
  const void* pb_ih1 = d_in[18];
  const void* pb_hh1 = d_in[19];
  const void* pfc_w  = d_in[20];
  const void* pfc_b  = d_in[21];

  char* ws = (char*)d_ws;
  Hdr* hdr = (Hdr*)ws;
  int* xt  = (int*)(ws + OFF_XT);
  int* flg = (int*)(ws + OFF_FLG);
  float* oA = (float*)(ws + OFF_OP);
  int* prb = (int*)(ws + OFF_PRB);
  short* H0R = (short*)(ws + OFF_H0);
  short* H1R = (short*)(ws + OFF_H1);
  short* Wc[6];
  for (int i = 0; i < 6; ++i) Wc[i] = (short*)(ws + OFF_W + (size_t)i*WSZ);

  hipMemsetAsync(ws, 0, OFF_H0, stream);           // hdr+xt+flags+op+probe
  hipMemsetAsync(ws + OFF_H0, 0, 1048576, stream); // h rings
  probe1_kernel<<<dim3(1), dim3(256), 0, stream>>>(w_hh0, hdr);

  dim3 cg(1024), cb(256);
  cvt_kernel<<<cg, cb, 0, stream>>>(w_hh0,  Wc[0], hdr);
  cvt_kernel<<<cg, cb, 0, stream>>>(w_ih1,  Wc[1], hdr);
  cvt_kernel<<<cg, cb, 0, stream>>>(w_hh1,  Wc[2], hdr);
  cvt_kernel<<<cg, cb, 0, stream>>>(pw_hh0, Wc[3], hdr);
  cvt_kernel<<<cg, cb, 0, stream>>>(pw_ih1, Wc[4], hdr);
  cvt_kernel<<<cg, cb, 0, stream>>>(pw_hh1, Wc[5], hdr);

  lstm_persist<<<dim3(NBLK), dim3(512), 0, stream>>>(
      x, w_ih0, b_ih0, b_hh0, b_ih1, b_hh1, fc_w, fc_b,
      pw_ih0, pb_ih0, pb_hh0, pb_ih1, pb_hh1, pfc_w, pfc_b,
      Wc[0], Wc[1], Wc[2], Wc[3], Wc[4], Wc[5],
      H0R, H1R, oA, xt, flg, prb, hdr, dout);
}